// Round 7
// baseline (1002.026 us; speedup 1.0000x reference)
//
#include <hip/hip_runtime.h>
#include <cstdint>
#include <cstddef>

// Problem: B=4, H=16, S=2048, DK=64; out = (attn@V, attn), fp32.
#define S_LEN 2048
#define DKD   64
#define BQ    64
#define BK    128
#define NKT   16
#define BDIM  256

typedef float f32x4 __attribute__((ext_vector_type(4)));
typedef short s16x8 __attribute__((ext_vector_type(8)));
typedef short s16x4 __attribute__((ext_vector_type(4)));
typedef unsigned int u32x4 __attribute__((ext_vector_type(4)));
typedef unsigned short u16t;
typedef unsigned long long u64t;

__device__ __forceinline__ u16t f2bf(float f) {  // RNE fp32->bf16
  unsigned u = __builtin_bit_cast(unsigned, f);
  return (u16t)((u + 0x7FFFu + ((u >> 16) & 1u)) >> 16);
}

// ---------- fused prologue: pack mask bits + K->bf16 (row-major) + V->bf16 V^T ----------
__global__ __launch_bounds__(256)
void prologue(const unsigned char* __restrict__ Mg, const float* __restrict__ Kg,
              const float* __restrict__ Vg, u64t* __restrict__ bits,
              u16t* __restrict__ Kws, u16t* __restrict__ Vws) {
  __shared__ float scr[BK][DKD + 1];
  __shared__ int mflag_s;
  const int tid = threadIdx.x;
  const int bid = blockIdx.x;

  if (bid < 1024) {            // ---- pack mask -> 1 bit per element ----
    int f = 0;                 // bool(1B) vs int32(4B) detection
    for (int i = tid; i < 4096; i += 256) if ((i & 3) && Mg[i]) f = 1;
    if (tid == 0) mflag_s = 0;
    __syncthreads();
    if (f) mflag_s = 1;
    __syncthreads();
    const int mstride = mflag_s ? 1 : 4;

    const int row = bid * 8 + (tid >> 5);    // 8192 rows (b*S+q)
    const int wd  = tid & 31;
    const size_t kbase = (size_t)row * S_LEN + (size_t)wd * 64;
    u64t word = 0;
    if (mstride == 1) {
      const u64t* p = (const u64t*)(Mg + kbase);
      #pragma unroll
      for (int i = 0; i < 8; ++i) {
        u64t x = p[i];
        u64t nz = x | (x >> 4); nz |= nz >> 2; nz |= nz >> 1;
        nz &= 0x0101010101010101ull;
        word |= ((nz * 0x0102040810204080ull) >> 56) << (8 * i);
      }
    } else {
      const unsigned* p = (const unsigned*)Mg + kbase;
      #pragma unroll
      for (int i = 0; i < 64; ++i) word |= (u64t)(p[i] ? 1u : 0u) << i;
    }
    bits[(size_t)row * 32 + wd] = word;
  } else if (bid < 2048) {     // ---- K fp32 -> bf16, plain row-major copy-cast ----
    const int kb = bid - 1024;
    #pragma unroll
    for (int i = 0; i < 4; ++i) {
      size_t cidx = (size_t)kb * 1024 + i * 256 + tid;     // 8-elem chunks
      const float4* s4 = (const float4*)Kg + 2 * cidx;
      float4 a = s4[0], b = s4[1];
      s16x8 h = { (short)f2bf(a.x), (short)f2bf(a.y), (short)f2bf(a.z), (short)f2bf(a.w),
                  (short)f2bf(b.x), (short)f2bf(b.y), (short)f2bf(b.z), (short)f2bf(b.w) };
      *((s16x8*)Kws + cidx) = h;
    }
  } else {                     // ---- V fp32 [k][dv] -> bf16 V^T [bh][dv][k], plain ----
    const int vb = bid - 2048;
    const int bh = vb >> 4, kb = vb & 15;
    const float4* src = (const float4*)(Vg + (size_t)vb * (BK * DKD));
    #pragma unroll
    for (int i = 0; i < 8; ++i) {
      int c = tid + 256 * i;
      float4 v = src[c];
      int k = c >> 4, d0 = (c & 15) * 4;
      scr[k][d0] = v.x; scr[k][d0 + 1] = v.y; scr[k][d0 + 2] = v.z; scr[k][d0 + 3] = v.w;
    }
    __syncthreads();
    #pragma unroll
    for (int i = 0; i < 8; ++i) {
      int c = tid + 256 * i;                 // dv = c>>5, chunk of 4 k
      int dv = c >> 5, k0 = (c & 31) * 4;
      ushort4 h = make_ushort4(f2bf(scr[k0][dv]), f2bf(scr[k0 + 1][dv]),
                               f2bf(scr[k0 + 2][dv]), f2bf(scr[k0 + 3][dv]));
      *(ushort4*)(Vws + ((size_t)bh * DKD + dv) * S_LEN + (size_t)kb * BK + k0) = h;
    }
  }
}

// ---------- fused attention: zero LDS, zero barriers; fragments direct from L2 ----------
__global__ __launch_bounds__(256, 3)
void attn_ws(const float* __restrict__ Qg, const u16t* __restrict__ Kbf,
             const u16t* __restrict__ Vt, const u64t* __restrict__ bits,
             float* __restrict__ outg, float* __restrict__ attng) {
  const int tid = threadIdx.x;
  const int p = blockIdx.x;
  const int qb = (p >> 3) & 31;                 // XCD swizzle: bh pinned per XCD
  const int bh = (p & 7) + 8 * (p >> 8);
  const int b  = bh >> 4;
  const int lane = tid & 63, wv = tid >> 6;
  const int cl = lane & 15, g = lane >> 4;
  const int qrow = qb * BQ + 16 * wv + cl;      // this lane's q row (swapped layout)

  const u16t* Kb = Kbf + (size_t)bh * S_LEN * DKD;
  const u16t* Vb = Vt  + (size_t)bh * DKD * S_LEN;
  const u64t* bitR = bits + (size_t)(b * S_LEN + qrow) * 32;
  float* aRow = attng + ((size_t)bh * S_LEN + qrow) * S_LEN;

  // Q B-fragments straight from fp32 Q (one-time)
  s16x8 aq0, aq1;
  {
    const float* qr = Qg + ((size_t)bh * S_LEN + qrow) * DKD;
    float x[8], y[8];
    *(float4*)(x)     = *(const float4*)(qr + 8 * g);
    *(float4*)(x + 4) = *(const float4*)(qr + 8 * g + 4);
    *(float4*)(y)     = *(const float4*)(qr + 32 + 8 * g);
    *(float4*)(y + 4) = *(const float4*)(qr + 32 + 8 * g + 4);
    #pragma unroll
    for (int j = 0; j < 8; ++j) { aq0[j] = (short)f2bf(x[j]); aq1[j] = (short)f2bf(y[j]); }
  }

  // ================= phase 1: row-sums (no-max softmax) =================
  float lsum = 0.f;
  for (int kt = 0; kt < NKT; ++kt) {
    ulonglong2 bw = *(const ulonglong2*)(bitR + 2 * kt);
    const u16t* Kt = Kb + (size_t)kt * (BK * DKD);
    #pragma unroll
    for (int s = 0; s < 8; ++s) {
      const u16t* kr = Kt + (16 * s + cl) * DKD;
      s16x8 k0 = *(const s16x8*)(kr + 8 * g);
      s16x8 k1 = *(const s16x8*)(kr + 32 + 8 * g);
      f32x4 acc = {0.f, 0.f, 0.f, 0.f};
      acc = __builtin_amdgcn_mfma_f32_16x16x32_bf16(k0, aq0, acc, 0, 0, 0);  // S^T
      acc = __builtin_amdgcn_mfma_f32_16x16x32_bf16(k1, aq1, acc, 0, 0, 0);
      unsigned nib = (unsigned)(((s < 4) ? bw.x : bw.y) >> (16 * (s & 3) + 4 * g)) & 0xFu;
      #pragma unroll
      for (int r = 0; r < 4; ++r)
        lsum += ((nib >> r) & 1) ? 0.f : __expf(acc[r] * 0.125f);
    }
  }
  lsum += __shfl_xor(lsum, 16);
  lsum += __shfl_xor(lsum, 32);
  const float rinv = 1.f / lsum;

  // ================= phase 2: recompute, direct fp32 attn stores, PV =================
  f32x4 accpv[4];
  #pragma unroll
  for (int db = 0; db < 4; ++db) accpv[db] = (f32x4){0.f, 0.f, 0.f, 0.f};

  for (int kt = 0; kt < NKT; ++kt) {
    ulonglong2 bw = *(const ulonglong2*)(bitR + 2 * kt);
    const u16t* Kt = Kb + (size_t)kt * (BK * DKD);
    const u16t* Vk = Vb + (size_t)kt * BK;       // column offset within V^T rows
    float* aKt = aRow + kt * BK;

    #pragma unroll
    for (int ks = 0; ks < 4; ++ks) {
      f32x4 qa[2];
      #pragma unroll
      for (int sp = 0; sp < 2; ++sp) {
        int s = 2 * ks + sp;
        const u16t* kr = Kt + (16 * s + cl) * DKD;
        s16x8 k0 = *(const s16x8*)(kr + 8 * g);
        s16x8 k1 = *(const s16x8*)(kr + 32 + 8 * g);
        f32x4 acc = {0.f, 0.f, 0.f, 0.f};
        acc = __builtin_amdgcn_mfma_f32_16x16x32_bf16(k0, aq0, acc, 0, 0, 0);
        acc = __builtin_amdgcn_mfma_f32_16x16x32_bf16(k1, aq1, acc, 0, 0, 0);
        qa[sp] = acc;
      }
      unsigned hw[4];
      #pragma unroll
      for (int sp = 0; sp < 2; ++sp) {
        int s = 2 * ks + sp;
        unsigned nib = (unsigned)(((s < 4) ? bw.x : bw.y) >> (16 * (s & 3) + 4 * g)) & 0xFu;
        f32x4 pv4;
        #pragma unroll
        for (int r = 0; r < 4; ++r)
          pv4[r] = ((nib >> r) & 1) ? 0.f : __expf(qa[sp][r] * 0.125f) * rinv;
        // direct fp32 attn store: lane holds P[q=qrow][k=16s+4g+r]; 4 g-lanes = one 64B line
        __builtin_nontemporal_store(pv4, (f32x4*)(aKt + 16 * s + 4 * g));
        hw[2 * sp + 0] = (unsigned)f2bf(pv4[0]) | ((unsigned)f2bf(pv4[1]) << 16);
        hw[2 * sp + 1] = (unsigned)f2bf(pv4[2]) | ((unsigned)f2bf(pv4[3]) << 16);
      }
      s16x8 pa = __builtin_bit_cast(s16x8, (u32x4){hw[0], hw[1], hw[2], hw[3]});
      #pragma unroll
      for (int db = 0; db < 4; ++db) {
        const u16t* vr = Vk + (size_t)(16 * db + cl) * S_LEN + 32 * ks + 4 * g;
        s16x4 v0 = *(const s16x4*)(vr);
        s16x4 v1 = *(const s16x4*)(vr + 16);
        s16x8 vb = __builtin_shufflevector(v0, v1, 0, 1, 2, 3, 4, 5, 6, 7);
        accpv[db] = __builtin_amdgcn_mfma_f32_16x16x32_bf16(pa, vb, accpv[db], 0, 0, 0);
      }
    }
  }

  // out: C rows (4g+r) = q, col (16db+cl) = dv  (validated R2-R5 mapping)
  const int q0 = qb * BQ + 16 * wv + 4 * g;
  #pragma unroll
  for (int r = 0; r < 4; ++r) {
    float* orow = outg + (size_t)(bh * S_LEN + q0 + r) * DKD + cl;
    #pragma unroll
    for (int db = 0; db < 4; ++db) orow[16 * db] = accpv[db][r];
  }
}

// ---------- fallback (self-contained, R2-proven structure) ----------
#define FB_KSTR 144
#define FB_VOFF (BK * FB_KSTR)
#define FB_VSTR 272
#define FB_POFF (FB_VOFF + DKD * FB_VSTR)
#define FB_SMEM (FB_POFF + BQ * FB_VSTR)

__global__ __launch_bounds__(256)
void attn_fb(const float* __restrict__ Qg, const float* __restrict__ Kg,
             const float* __restrict__ Vg, const unsigned char* __restrict__ Mg,
             float* __restrict__ outg, float* __restrict__ attng) {
  __shared__ char smem[FB_SMEM];
  __shared__ int mflag_s;
  const int tid = threadIdx.x;
  const int p = blockIdx.x;
  const int qb = (p >> 3) & 31;
  const int bh = (p & 7) + 8 * (p >> 8);
  const int b  = bh >> 4;

  int f = 0;
  for (int i = tid; i < 4096; i += BDIM) if ((i & 3) && Mg[i]) f = 1;
  if (tid == 0) mflag_s = 0;
  __syncthreads();
  if (f) mflag_s = 1;
  __syncthreads();
  const int mstride = mflag_s ? 1 : 4;

  const int lane = tid & 63, wv = tid >> 6;
  const int cl = lane & 15, g = lane >> 4;
  const int q0 = qb * BQ + 16 * wv + 4 * g;

  const float* Kbh = Kg + (size_t)bh * S_LEN * DKD;
  const float* Vbh = Vg + (size_t)bh * S_LEN * DKD;

  float* aRow[4]; float* oRow[4]; const unsigned char* mRow[4];
  #pragma unroll
  for (int r = 0; r < 4; ++r) {
    aRow[r] = attng + (size_t)(bh * S_LEN + q0 + r) * S_LEN + cl;
    oRow[r] = outg + (size_t)(bh * S_LEN + q0 + r) * DKD + cl;
    mRow[r] = Mg + ((size_t)(b * S_LEN + q0 + r) * S_LEN + cl) * (size_t)mstride;
  }

  s16x8 aq0, aq1;
  {
    const float* qrow = Qg + ((size_t)bh * S_LEN + qb * BQ + 16 * wv + cl) * DKD;
    float x[8], y[8];
    *(float4*)(x)     = *(const float4*)(qrow + 8 * g);
    *(float4*)(x + 4) = *(const float4*)(qrow + 8 * g + 4);
    *(float4*)(y)     = *(const float4*)(qrow + 32 + 8 * g);
    *(float4*)(y + 4) = *(const float4*)(qrow + 32 + 8 * g + 4);
    #pragma unroll
    for (int j = 0; j < 8; ++j) { aq0[j] = (short)f2bf(x[j]); aq1[j] = (short)f2bf(y[j]); }
  }

  float lsum[4] = {0.f, 0.f, 0.f, 0.f};
  for (int kt = 0; kt < NKT; ++kt) {
    const float4* ksrc = (const float4*)(Kbh + (size_t)kt * (BK * DKD));
    #pragma unroll
    for (int it = 0; it < 8; ++it) {
      int c = tid + BDIM * it;
      float4 v = ksrc[c];
      *(ushort4*)(smem + (c >> 4) * FB_KSTR + (c & 15) * 8) =
          make_ushort4(f2bf(v.x), f2bf(v.y), f2bf(v.z), f2bf(v.w));
    }
    __syncthreads();
    #pragma unroll
    for (int s = 0; s < 8; ++s) {
      s16x8 b0 = *(const s16x8*)(smem + (16 * s + cl) * FB_KSTR + 16 * g);
      s16x8 b1 = *(const s16x8*)(smem + (16 * s + cl) * FB_KSTR + 64 + 16 * g);
      f32x4 acc = {0.f, 0.f, 0.f, 0.f};
      acc = __builtin_amdgcn_mfma_f32_16x16x32_bf16(aq0, b0, acc, 0, 0, 0);
      acc = __builtin_amdgcn_mfma_f32_16x16x32_bf16(aq1, b1, acc, 0, 0, 0);
      #pragma unroll
      for (int r = 0; r < 4; ++r) {
        bool mk = mRow[r][(size_t)(kt * BK + 16 * s) * mstride] != 0;
        lsum[r] += mk ? 0.f : __expf(acc[r] * 0.125f);
      }
    }
    __syncthreads();
  }
  float rinv[4];
  #pragma unroll
  for (int r = 0; r < 4; ++r) {
    float l = lsum[r];
    #pragma unroll
    for (int d = 1; d < 16; d <<= 1) l += __shfl_xor(l, d);
    rinv[r] = 1.f / l;
  }

  f32x4 accpv[4];
  #pragma unroll
  for (int db = 0; db < 4; ++db) accpv[db] = (f32x4){0.f, 0.f, 0.f, 0.f};

  for (int kt = 0; kt < NKT; ++kt) {
    const float4* ksrc = (const float4*)(Kbh + (size_t)kt * (BK * DKD));
    #pragma unroll
    for (int it = 0; it < 8; ++it) {
      int c = tid + BDIM * it;
      float4 v = ksrc[c];
      *(ushort4*)(smem + (c >> 4) * FB_KSTR + (c & 15) * 8) =
          make_ushort4(f2bf(v.x), f2bf(v.y), f2bf(v.z), f2bf(v.w));
    }
    const float4* vsrc = (const float4*)(Vbh + (size_t)kt * (BK * DKD));
    #pragma unroll
    for (int it = 0; it < 8; ++it) {
      int c = tid + BDIM * it;
      float4 v = vsrc[c];
      int k = c >> 4, d0 = (c & 15) * 4;
      *(u16t*)(smem + FB_VOFF + (d0 + 0) * FB_VSTR + k * 2) = f2bf(v.x);
      *(u16t*)(smem + FB_VOFF + (d0 + 1) * FB_VSTR + k * 2) = f2bf(v.y);
      *(u16t*)(smem + FB_VOFF + (d0 + 2) * FB_VSTR + k * 2) = f2bf(v.z);
      *(u16t*)(smem + FB_VOFF + (d0 + 3) * FB_VSTR + k * 2) = f2bf(v.w);
    }
    __syncthreads();

    #pragma unroll
    for (int ks = 0; ks < 4; ++ks) {
      f32x4 qa[2];
      #pragma unroll
      for (int sp = 0; sp < 2; ++sp) {
        int s = 2 * ks + sp;
        s16x8 b0 = *(const s16x8*)(smem + (16 * s + cl) * FB_KSTR + 16 * g);
        s16x8 b1 = *(const s16x8*)(smem + (16 * s + cl) * FB_KSTR + 64 + 16 * g);
        f32x4 acc = {0.f, 0.f, 0.f, 0.f};
        acc = __builtin_amdgcn_mfma_f32_16x16x32_bf16(aq0, b0, acc, 0, 0, 0);
        acc = __builtin_amdgcn_mfma_f32_16x16x32_bf16(aq1, b1, acc, 0, 0, 0);
        qa[sp] = acc;
      }
      #pragma unroll
      for (int sp = 0; sp < 2; ++sp) {
        int s = 2 * ks + sp;
        #pragma unroll
        for (int r = 0; r < 4; ++r) {
          bool mk = mRow[r][(size_t)(kt * BK + 16 * s) * mstride] != 0;
          float pv = mk ? 0.f : __expf(qa[sp][r] * 0.125f) * rinv[r];
          __builtin_nontemporal_store(pv, aRow[r] + kt * BK + 16 * s);
          *(u16t*)(smem + FB_POFF + (16 * wv + 4 * g + r) * FB_VSTR +
                   (32 * ks + 16 * sp + cl) * 2) = f2bf(pv);
        }
      }
      s16x4 p0 = *(const s16x4*)(smem + FB_POFF + (16 * wv + cl) * FB_VSTR + (32 * ks + 4 * g) * 2);
      s16x4 p1 = *(const s16x4*)(smem + FB_POFF + (16 * wv + cl) * FB_VSTR + (32 * ks + 16 + 4 * g) * 2);
      s16x8 pa = __builtin_shufflevector(p0, p1, 0, 1, 2, 3, 4, 5, 6, 7);
      #pragma unroll
      for (int db = 0; db < 4; ++db) {
        s16x4 v0 = *(const s16x4*)(smem + FB_VOFF + (16 * db + cl) * FB_VSTR + (32 * ks + 4 * g) * 2);
        s16x4 v1 = *(const s16x4*)(smem + FB_VOFF + (16 * db + cl) * FB_VSTR + (32 * ks + 16 + 4 * g) * 2);
        s16x8 vb = __builtin_shufflevector(v0, v1, 0, 1, 2, 3, 4, 5, 6, 7);
        accpv[db] = __builtin_amdgcn_mfma_f32_16x16x32_bf16(pa, vb, accpv[db], 0, 0, 0);
      }
    }
    __syncthreads();
  }

  #pragma unroll
  for (int db = 0; db < 4; ++db)
    #pragma unroll
    for (int r = 0; r < 4; ++r)
      oRow[r][16 * db] = accpv[db][r];
}

extern "C" void kernel_launch(void* const* d_in, const int* in_sizes, int n_in,
                              void* d_out, int out_size, void* d_ws, size_t ws_size,
                              hipStream_t stream) {
  const float* Q = (const float*)d_in[0];
  const float* K = (const float*)d_in[1];
  const float* V = (const float*)d_in[2];
  const unsigned char* M = (const unsigned char*)d_in[3];
  float* out = (float*)d_out;
  float* attn = out + (size_t)4 * 16 * S_LEN * DKD;

  const size_t BITS_SZ = (size_t)4 * S_LEN * 32 * 8;              // 2 MB
  const size_t KWS_SZ  = (size_t)64 * S_LEN * DKD * 2;            // 16 MB
  const size_t VWS_SZ  = (size_t)64 * DKD * S_LEN * 2;            // 16 MB
  if (ws_size >= BITS_SZ + KWS_SZ + VWS_SZ) {
    u64t* bits = (u64t*)d_ws;
    u16t* Kws = (u16t*)((char*)d_ws + BITS_SZ);
    u16t* Vws = (u16t*)((char*)d_ws + BITS_SZ + KWS_SZ);
    prologue<<<3072, 256, 0, stream>>>(M, K, V, bits, Kws, Vws);
    attn_ws<<<2048, BDIM, 0, stream>>>(Q, Kws, Vws, bits, out, attn);
  } else {
    attn_fb<<<2048, BDIM, 0, stream>>>(Q, K, V, M, out, attn);
  }
}

// Round 8
// 338.234 us; speedup vs baseline: 2.9625x; 2.9625x over previous
//
#include <hip/hip_runtime.h>
#include <cstdint>
#include <cstddef>

// Problem: B=4, H=16, S=2048, DK=64; out = (attn@V, attn), fp32.
#define S_LEN 2048
#define DKD   64
#define BQ    64
#define BK    128
#define NKT   16
#define BDIM  256

typedef float f32x4 __attribute__((ext_vector_type(4)));
typedef short s16x8 __attribute__((ext_vector_type(8)));
typedef short s16x4 __attribute__((ext_vector_type(4)));
typedef unsigned int u32x4 __attribute__((ext_vector_type(4)));
typedef unsigned short u16t;
typedef unsigned long long u64t;

// ---- LDS layout for attn_ws (bytes) ----
#define KS_OFF    0
#define KT_BYTES  (BK * DKD * 2)              // 16384, linear rows of 128B
#define VT_OFF    16384                        // phase2: V^T tile; phase1: K buffer 1
#define VT_BYTES  (DKD * BK * 2)              // 16384, linear rows of 256B
#define PS_OFF    32768
#define PS_STRIDE 280
#define SMEM_SZ   (PS_OFF + BQ * PS_STRIDE)   // 50688 -> 3 blocks/CU

__device__ __forceinline__ u16t f2bf(float f) {  // RNE fp32->bf16
  unsigned u = __builtin_bit_cast(unsigned, f);
  return (u16t)((u + 0x7FFFu + ((u >> 16) & 1u)) >> 16);
}
__device__ __forceinline__ float bf_lo(unsigned u) {
  return __builtin_bit_cast(float, u << 16);
}
__device__ __forceinline__ float bf_hi(unsigned u) {
  return __builtin_bit_cast(float, u & 0xFFFF0000u);
}

__device__ __forceinline__ void gl_lds16(const void* g, void* l) {
  typedef __attribute__((address_space(1))) void gvoid;
  typedef __attribute__((address_space(3))) void lvoid;
  __builtin_amdgcn_global_load_lds((gvoid*)(void*)g, (lvoid*)l, 16, 0, 0);
}

// counted barriers. sched_barrier(0) after, per rule #18.
#define BAR_VM(N) do { asm volatile("s_waitcnt vmcnt(" #N ")\n\ts_barrier" ::: "memory"); \
                       __builtin_amdgcn_sched_barrier(0); } while (0)
#define BAR_LG()  do { asm volatile("s_waitcnt lgkmcnt(0)\n\ts_barrier" ::: "memory"); \
                       __builtin_amdgcn_sched_barrier(0); } while (0)
#define BAR_VM8() do { asm volatile("s_waitcnt vmcnt(8) lgkmcnt(0)\n\ts_barrier" ::: "memory"); \
                       __builtin_amdgcn_sched_barrier(0); } while (0)

// ---------- fused prologue: pack mask bits + K->bf16 tiles + V->bf16^T tiles ----------
__global__ __launch_bounds__(256)
void prologue(const unsigned char* __restrict__ Mg, const float* __restrict__ Kg,
              const float* __restrict__ Vg, u64t* __restrict__ bits,
              u16t* __restrict__ Kws, u16t* __restrict__ Vws) {
  __shared__ float scr[BK][DKD + 1];
  __shared__ int mflag_s;
  const int tid = threadIdx.x;
  const int bid = blockIdx.x;

  if (bid < 1024) {            // ---- pack mask -> 1 bit per element ----
    int f = 0;                 // bool(1B) vs int32(4B) detection
    for (int i = tid; i < 4096; i += 256) if ((i & 3) && Mg[i]) f = 1;
    if (tid == 0) mflag_s = 0;
    __syncthreads();
    if (f) mflag_s = 1;
    __syncthreads();
    const int mstride = mflag_s ? 1 : 4;

    const int row = bid * 8 + (tid >> 5);    // 8192 rows (b*S+q)
    const int wd  = tid & 31;
    const size_t kbase = (size_t)row * S_LEN + (size_t)wd * 64;
    u64t word = 0;
    if (mstride == 1) {
      const u64t* p = (const u64t*)(Mg + kbase);
      #pragma unroll
      for (int i = 0; i < 8; ++i) {
        u64t x = p[i];
        u64t nz = x | (x >> 4); nz |= nz >> 2; nz |= nz >> 1;
        nz &= 0x0101010101010101ull;
        word |= ((nz * 0x0102040810204080ull) >> 56) << (8 * i);
      }
    } else {
      const unsigned* p = (const unsigned*)Mg + kbase;
      #pragma unroll
      for (int i = 0; i < 64; ++i) word |= (u64t)(p[i] ? 1u : 0u) << i;
    }
    bits[(size_t)row * 32 + wd] = word;
  } else if (bid < 2048) {     // ---- K fp32 -> bf16 tiles, 16B-chunk XOR-permuted ----
    const int kb = bid - 1024;
    const float* src = Kg + (size_t)kb * (BK * DKD);
    u16t* dst = Kws + (size_t)kb * (BK * DKD);
    #pragma unroll
    for (int i = 0; i < 4; ++i) {
      int c = tid + 256 * i;                 // 1024 chunks of 8 elems (16B)
      int row = c >> 3, y = c & 7;
      int oc = y ^ (row & 7);
      const float4* s4 = (const float4*)(src + row * DKD + 8 * oc);
      float4 a = s4[0], b = s4[1];
      s16x8 h = { (short)f2bf(a.x), (short)f2bf(a.y), (short)f2bf(a.z), (short)f2bf(a.w),
                  (short)f2bf(b.x), (short)f2bf(b.y), (short)f2bf(b.z), (short)f2bf(b.w) };
      *(s16x8*)(dst + row * DKD + 8 * y) = h;
    }
  } else {                     // ---- V fp32 [k][dv] -> bf16 V^T tiles, 8B-chunk XOR-permuted ----
    const int vb = bid - 2048;
    const float4* src = (const float4*)(Vg + (size_t)vb * (BK * DKD));
    #pragma unroll
    for (int i = 0; i < 8; ++i) {
      int c = tid + 256 * i;
      float4 v = src[c];
      int k = c >> 4, d0 = (c & 15) * 4;
      scr[k][d0] = v.x; scr[k][d0 + 1] = v.y; scr[k][d0 + 2] = v.z; scr[k][d0 + 3] = v.w;
    }
    __syncthreads();
    u16t* dst = Vws + (size_t)vb * (DKD * BK);
    #pragma unroll
    for (int i = 0; i < 8; ++i) {
      int c = tid + 256 * i;                 // 2048 chunks of 4 elems (8B)
      int dv = c >> 5, y = c & 31;
      int k0 = 4 * (y ^ (dv & 7));
      ushort4 h = make_ushort4(f2bf(scr[k0][dv]), f2bf(scr[k0 + 1][dv]),
                               f2bf(scr[k0 + 2][dv]), f2bf(scr[k0 + 3][dv]));
      *(ushort4*)(dst + dv * BK + 4 * y) = h;
    }
  }
}

// ---------- fused attention, ws path (swapped QK^T: P is lane-local) ----------
__global__ __launch_bounds__(256)
void attn_ws(const float* __restrict__ Qg, const u16t* __restrict__ Kws,
             const u16t* __restrict__ Vws, const u64t* __restrict__ bits,
             float* __restrict__ outg, float* __restrict__ attng) {
  __shared__ char smem[SMEM_SZ];
  const int tid = threadIdx.x;
  const int p = blockIdx.x;
  const int qb = (p >> 3) & 31;                 // XCD swizzle: bh pinned per XCD
  const int bh = (p & 7) + 8 * (p >> 8);
  const int b  = bh >> 4;
  const int lane = tid & 63, wv = tid >> 6;
  const int cl = lane & 15, g = lane >> 4;
  const int qrow = qb * BQ + 16 * wv + cl;      // this lane's q row (swapped layout)
  const int swzK = (cl & 7) << 4;               // read-side XOR, 16B chunks
  const int swzV = (cl & 7) << 3;               // read-side XOR, 8B chunks

  const char* Kbh = (const char*)Kws + (size_t)bh * NKT * KT_BYTES;
  const char* Vbh = (const char*)Vws + (size_t)bh * NKT * VT_BYTES;
  const u64t* bitR = bits + (size_t)(b * S_LEN + qrow) * 32;
  float* attnQ = attng + ((size_t)bh * S_LEN + (size_t)qb * BQ) * S_LEN;

  // Q B-fragments straight from fp32 Q (one-time). 1/8 scale folded into Q:
  // bf16(Q/8) == bf16(Q)/8 exactly (pure exponent shift), so QK^T acc is pre-scaled.
  s16x8 aq0, aq1;
  {
    const float* qr = Qg + ((size_t)bh * S_LEN + qrow) * DKD;
    float x[8], y[8];
    *(float4*)(x)     = *(const float4*)(qr + 8 * g);
    *(float4*)(x + 4) = *(const float4*)(qr + 8 * g + 4);
    *(float4*)(y)     = *(const float4*)(qr + 32 + 8 * g);
    *(float4*)(y + 4) = *(const float4*)(qr + 32 + 8 * g + 4);
    #pragma unroll
    for (int j = 0; j < 8; ++j) {
      aq0[j] = (short)f2bf(x[j] * 0.125f);
      aq1[j] = (short)f2bf(y[j] * 0.125f);
    }
  }

  auto stageK = [&](int kt, int off) {
    const char* src = Kbh + (size_t)kt * KT_BYTES + wv * 4096 + lane * 16;
    #pragma unroll
    for (int t = 0; t < 4; ++t)
      gl_lds16(src + t * 1024, (void*)(smem + off + wv * 4096 + t * 1024));
  };
  auto stageV = [&](int kt) {
    const char* src = Vbh + (size_t)kt * VT_BYTES + wv * 4096 + lane * 16;
    #pragma unroll
    for (int t = 0; t < 4; ++t)
      gl_lds16(src + t * 1024, (void*)(smem + VT_OFF + wv * 4096 + t * 1024));
  };

  // ================= phase 1: row-sums (no-max softmax), K dbuf =================
  // T3-min single-barrier loop: stage(next) -> compute(cur) -> vmcnt(0)+barrier.
  // Safe: by barrier arrival every wave's ds_reads of cur were consumed by MFMA,
  // so next iteration's stage into the other buffer cannot race reads.
  float lsum = 0.f;
  stageK(0, KS_OFF);
  BAR_VM(0);                       // tile 0 resident for all waves
  for (int kt = 0; kt < NKT; ++kt) {
    const int cur = (kt & 1) ? VT_OFF : KS_OFF;
    if (kt + 1 < NKT) stageK(kt + 1, (kt & 1) ? KS_OFF : VT_OFF);
    ulonglong2 bw = *(const ulonglong2*)(bitR + 2 * kt);
    #pragma unroll
    for (int s = 0; s < 8; ++s) {
      const char* rb = smem + cur + (16 * s + cl) * 128;
      s16x8 k0 = *(const s16x8*)(rb + ((16 * g) ^ swzK));
      s16x8 k1 = *(const s16x8*)(rb + ((64 + 16 * g) ^ swzK));
      f32x4 acc = {0.f, 0.f, 0.f, 0.f};
      acc = __builtin_amdgcn_mfma_f32_16x16x32_bf16(k0, aq0, acc, 0, 0, 0);  // S^T (pre-scaled)
      acc = __builtin_amdgcn_mfma_f32_16x16x32_bf16(k1, aq1, acc, 0, 0, 0);
      unsigned nib = (unsigned)(((s < 4) ? bw.x : bw.y) >> (16 * (s & 3) + 4 * g)) & 0xFu;
      #pragma unroll
      for (int r = 0; r < 4; ++r)
        lsum += ((nib >> r) & 1) ? 0.f : __expf(acc[r]);
    }
    if (kt + 1 < NKT) BAR_VM(0);   // next tile arrived; single barrier per kt
  }
  BAR_LG();                        // all waves done reading last tile
  stageK(0, KS_OFF);               // stage K0/V0 for phase 2; reduce meanwhile
  stageV(0);
  lsum += __shfl_xor(lsum, 16);
  lsum += __shfl_xor(lsum, 32);
  const float rinv = 1.f / lsum;
  BAR_VM(0);

  // ================= phase 2: recompute, in-reg pa, PV, attn write =================
  f32x4 accpv[4];
  #pragma unroll
  for (int db = 0; db < 4; ++db) accpv[db] = (f32x4){0.f, 0.f, 0.f, 0.f};

  for (int kt = 0; kt < NKT; ++kt) {
    // entering: K/V for kt resident; PS free
    ulonglong2 bw = *(const ulonglong2*)(bitR + 2 * kt);
    char* pbase = smem + PS_OFF + (16 * wv + cl) * PS_STRIDE;

    #pragma unroll
    for (int ks = 0; ks < 4; ++ks) {
      f32x4 qa[2];
      __builtin_amdgcn_s_setprio(1);
      #pragma unroll
      for (int sp = 0; sp < 2; ++sp) {
        int s = 2 * ks + sp;
        const char* rb = smem + KS_OFF + (16 * s + cl) * 128;
        s16x8 k0 = *(const s16x8*)(rb + ((16 * g) ^ swzK));
        s16x8 k1 = *(const s16x8*)(rb + ((64 + 16 * g) ^ swzK));
        f32x4 acc = {0.f, 0.f, 0.f, 0.f};
        acc = __builtin_amdgcn_mfma_f32_16x16x32_bf16(k0, aq0, acc, 0, 0, 0);
        acc = __builtin_amdgcn_mfma_f32_16x16x32_bf16(k1, aq1, acc, 0, 0, 0);
        qa[sp] = acc;
      }
      __builtin_amdgcn_s_setprio(0);
      unsigned hw[4];
      #pragma unroll
      for (int sp = 0; sp < 2; ++sp) {
        int s = 2 * ks + sp;
        unsigned nib = (unsigned)(((s < 4) ? bw.x : bw.y) >> (16 * (s & 3) + 4 * g)) & 0xFu;
        #pragma unroll
        for (int rr = 0; rr < 2; ++rr) {
          float p0 = ((nib >> (2 * rr)) & 1)     ? 0.f : __expf(qa[sp][2 * rr]) * rinv;
          float p1 = ((nib >> (2 * rr + 1)) & 1) ? 0.f : __expf(qa[sp][2 * rr + 1]) * rinv;
          hw[2 * sp + rr] = (unsigned)f2bf(p0) | ((unsigned)f2bf(p1) << 16);
        }
      }
      // PS write (for attn readback only) + in-register pa for PV
      *(uint2*)(pbase + 64 * ks + 8 * g)      = make_uint2(hw[0], hw[1]);
      *(uint2*)(pbase + 64 * ks + 32 + 8 * g) = make_uint2(hw[2], hw[3]);
      s16x8 pa = __builtin_bit_cast(s16x8, (u32x4){hw[0], hw[1], hw[2], hw[3]});
      __builtin_amdgcn_s_setprio(1);
      #pragma unroll
      for (int db = 0; db < 4; ++db) {
        const char* vrow = smem + VT_OFF + (16 * db + cl) * 256;
        s16x4 v0 = *(const s16x4*)(vrow + ((64 * ks + 8 * g) ^ swzV));
        s16x4 v1 = *(const s16x4*)(vrow + ((64 * ks + 32 + 8 * g) ^ swzV));
        s16x8 vb = __builtin_shufflevector(v0, v1, 0, 1, 2, 3, 4, 5, 6, 7);
        accpv[db] = __builtin_amdgcn_mfma_f32_16x16x32_bf16(pa, vb, accpv[db], 0, 0, 0);
      }
      __builtin_amdgcn_s_setprio(0);
    }

    BAR_LG();                    // PS visible; K/V LDS reads complete

    if (kt + 1 < NKT) { stageK(kt + 1, KS_OFF); stageV(kt + 1); }   // 8 gl_lds

    // readback PS -> coalesced fp32 attn stores (kept in flight across barrier)
    #pragma unroll
    for (int i = 0; i < 4; ++i) {
      int c = tid + 256 * i;
      int q = c >> 4, ch = c & 15;
      u32x4 d = *(const u32x4*)(smem + PS_OFF + q * PS_STRIDE + ch * 16);
      f32x4 lo = { bf_lo(d.x), bf_hi(d.x), bf_lo(d.y), bf_hi(d.y) };
      f32x4 hi = { bf_lo(d.z), bf_hi(d.z), bf_lo(d.w), bf_hi(d.w) };
      float* dst = attnQ + (size_t)q * S_LEN + kt * BK + ch * 8;
      __builtin_nontemporal_store(lo, (f32x4*)dst);
      __builtin_nontemporal_store(hi, (f32x4*)(dst + 4));
    }

    if (kt + 1 < NKT) BAR_VM8(); // gl_lds retired (FIFO: 8 younger stores float)
  }

  // out: C rows (4g+r) = q, col (16db+cl) = dv
  const int q0 = qb * BQ + 16 * wv + 4 * g;
  #pragma unroll
  for (int r = 0; r < 4; ++r) {
    float* orow = outg + (size_t)(bh * S_LEN + q0 + r) * DKD + cl;
    #pragma unroll
    for (int db = 0; db < 4; ++db) orow[16 * db] = accpv[db][r];
  }
}

// ---------- fallback (self-contained, R2-proven structure) ----------
#define FB_KSTR 144
#define FB_VOFF (BK * FB_KSTR)
#define FB_VSTR 272
#define FB_POFF (FB_VOFF + DKD * FB_VSTR)
#define FB_SMEM (FB_POFF + BQ * FB_VSTR)

__global__ __launch_bounds__(256)
void attn_fb(const float* __restrict__ Qg, const float* __restrict__ Kg,
             const float* __restrict__ Vg, const unsigned char* __restrict__ Mg,
             float* __restrict__ outg, float* __restrict__ attng) {
  __shared__ char smem[FB_SMEM];
  __shared__ int mflag_s;
  const int tid = threadIdx.x;
  const int p = blockIdx.x;
  const int qb = (p >> 3) & 31;
  const int bh = (p & 7) + 8 * (p >> 8);
  const int b  = bh >> 4;

  int f = 0;
  for (int i = tid; i < 4096; i += BDIM) if ((i & 3) && Mg[i]) f = 1;
  if (tid == 0) mflag_s = 0;
  __syncthreads();
  if (f) mflag_s = 1;
  __syncthreads();
  const int mstride = mflag_s ? 1 : 4;

  const int lane = tid & 63, wv = tid >> 6;
  const int cl = lane & 15, g = lane >> 4;
  const int q0 = qb * BQ + 16 * wv + 4 * g;

  const float* Kbh = Kg + (size_t)bh * S_LEN * DKD;
  const float* Vbh = Vg + (size_t)bh * S_LEN * DKD;

  float* aRow[4]; float* oRow[4]; const unsigned char* mRow[4];
  #pragma unroll
  for (int r = 0; r < 4; ++r) {
    aRow[r] = attng + (size_t)(bh * S_LEN + q0 + r) * S_LEN + cl;
    oRow[r] = outg + (size_t)(bh * S_LEN + q0 + r) * DKD + cl;
    mRow[r] = Mg + ((size_t)(b * S_LEN + q0 + r) * S_LEN + cl) * (size_t)mstride;
  }

  s16x8 aq0, aq1;
  {
    const float* qrow = Qg + ((size_t)bh * S_LEN + qb * BQ + 16 * wv + cl) * DKD;
    float x[8], y[8];
    *(float4*)(x)     = *(const float4*)(qrow + 8 * g);
    *(float4*)(x + 4) = *(const float4*)(qrow + 8 * g + 4);
    *(float4*)(y)     = *(const float4*)(qrow + 32 + 8 * g);
    *(float4*)(y + 4) = *(const float4*)(qrow + 32 + 8 * g + 4);
    #pragma unroll
    for (int j = 0; j < 8; ++j) { aq0[j] = (short)f2bf(x[j]); aq1[j] = (short)f2bf(y[j]); }
  }

  float lsum[4] = {0.f, 0.f, 0.f, 0.f};
  for (int kt = 0; kt < NKT; ++kt) {
    const float4* ksrc = (const float4*)(Kbh + (size_t)kt * (BK * DKD));
    #pragma unroll
    for (int it = 0; it < 8; ++it) {
      int c = tid + BDIM * it;
      float4 v = ksrc[c];
      *(ushort4*)(smem + (c >> 4) * FB_KSTR + (c & 15) * 8) =
          make_ushort4(f2bf(v.x), f2bf(v.y), f2bf(v.z), f2bf(v.w));
    }
    __syncthreads();
    #pragma unroll
    for (int s = 0; s < 8; ++s) {
      s16x8 b0 = *(const s16x8*)(smem + (16 * s + cl) * FB_KSTR + 16 * g);
      s16x8 b1 = *(const s16x8*)(smem + (16 * s + cl) * FB_KSTR + 64 + 16 * g);
      f32x4 acc = {0.f, 0.f, 0.f, 0.f};
      acc = __builtin_amdgcn_mfma_f32_16x16x32_bf16(aq0, b0, acc, 0, 0, 0);
      acc = __builtin_amdgcn_mfma_f32_16x16x32_bf16(aq1, b1, acc, 0, 0, 0);
      #pragma unroll
      for (int r = 0; r < 4; ++r) {
        bool mk = mRow[r][(size_t)(kt * BK + 16 * s) * mstride] != 0;
        lsum[r] += mk ? 0.f : __expf(acc[r] * 0.125f);
      }
    }
    __syncthreads();
  }
  float rinv[4];
  #pragma unroll
  for (int r = 0; r < 4; ++r) {
    float l = lsum[r];
    #pragma unroll
    for (int d = 1; d < 16; d <<= 1) l += __shfl_xor(l, d);
    rinv[r] = 1.f / l;
  }

  f32x4 accpv[4];
  #pragma unroll
  for (int db = 0; db < 4; ++db) accpv[db] = (f32x4){0.f, 0.f, 0.f, 0.f};

  for (int kt = 0; kt < NKT; ++kt) {
    const float4* ksrc = (const float4*)(Kbh + (size_t)kt * (BK * DKD));
    #pragma unroll
    for (int it = 0; it < 8; ++it) {
      int c = tid + BDIM * it;
      float4 v = ksrc[c];
      *(ushort4*)(smem + (c >> 4) * FB_KSTR + (c & 15) * 8) =
          make_ushort4(f2bf(v.x), f2bf(v.y), f2bf(v.z), f2bf(v.w));
    }
    const float4* vsrc = (const float4*)(Vbh + (size_t)kt * (BK * DKD));
    #pragma unroll
    for (int it = 0; it < 8; ++it) {
      int c = tid + BDIM * it;
      float4 v = vsrc[c];
      int k = c >> 4, d0 = (c & 15) * 4;
      *(u16t*)(smem + FB_VOFF + (d0 + 0) * FB_VSTR + k * 2) = f2bf(v.x);
      *(u16t*)(smem + FB_VOFF + (d0 + 1) * FB_VSTR + k * 2) = f2bf(v.y);
      *(u16t*)(smem + FB_VOFF + (d0 + 2) * FB_VSTR + k * 2) = f2bf(v.z);
      *(u16t*)(smem + FB_VOFF + (d0 + 3) * FB_VSTR + k * 2) = f2bf(v.w);
    }
    __syncthreads();

    #pragma unroll
    for (int ks = 0; ks < 4; ++ks) {
      f32x4 qa[2];
      #pragma unroll
      for (int sp = 0; sp < 2; ++sp) {
        int s = 2 * ks + sp;
        s16x8 b0 = *(const s16x8*)(smem + (16 * s + cl) * FB_KSTR + 16 * g);
        s16x8 b1 = *(const s16x8*)(smem + (16 * s + cl) * FB_KSTR + 64 + 16 * g);
        f32x4 acc = {0.f, 0.f, 0.f, 0.f};
        acc = __builtin_amdgcn_mfma_f32_16x16x32_bf16(aq0, b0, acc, 0, 0, 0);
        acc = __builtin_amdgcn_mfma_f32_16x16x32_bf16(aq1, b1, acc, 0, 0, 0);
        qa[sp] = acc;
      }
      #pragma unroll
      for (int sp = 0; sp < 2; ++sp) {
        int s = 2 * ks + sp;
        #pragma unroll
        for (int r = 0; r < 4; ++r) {
          bool mk = mRow[r][(size_t)(kt * BK + 16 * s) * mstride] != 0;
          float pv = mk ? 0.f : __expf(qa[sp][r] * 0.125f) * rinv[r];
          __builtin_nontemporal_store(pv, aRow[r] + kt * BK + 16 * s);
          *(u16t*)(smem + FB_POFF + (16 * wv + 4 * g + r) * FB_VSTR +
                   (32 * ks + 16 * sp + cl) * 2) = f2bf(pv);
        }
      }
      s16x4 p0 = *(const s16x4*)(smem + FB_POFF + (16 * wv + cl) * FB_VSTR + (32 * ks + 4 * g) * 2);
      s16x4 p1 = *(const s16x4*)(smem + FB_POFF + (16 * wv + cl) * FB_VSTR + (32 * ks + 16 + 4 * g) * 2);
      s16x8 pa = __builtin_shufflevector(p0, p1, 0, 1, 2, 3, 4, 5, 6, 7);
      #pragma unroll
      for (int db = 0; db < 4; ++db) {
        s16x4 v0 = *(const s16x4*)(smem + FB_VOFF + (16 * db + cl) * FB_VSTR + (32 * ks + 4 * g) * 2);
        s16x4 v1 = *(const s16x4*)(smem + FB_VOFF + (16 * db + cl) * FB_VSTR + (32 * ks + 16 + 4 * g) * 2);
        s16x8 vb = __builtin_shufflevector(v0, v1, 0, 1, 2, 3, 4, 5, 6, 7);
        accpv[db] = __builtin_amdgcn_mfma_f32_16x16x32_bf16(pa, vb, accpv[db], 0, 0, 0);
      }
    }
    __syncthreads();
  }

  #pragma unroll
  for (int db = 0; db < 4; ++db)
    #pragma unroll
    for (int r = 0; r < 4; ++r)
      oRow[r][16 * db] = accpv[db][r];
}

extern "C" void kernel_launch(void* const* d_in, const int* in_sizes, int n_in,
                              void* d_out, int out_size, void* d_ws, size_t ws_size,
                              hipStream_t stream) {
  const float* Q = (const float*)d_in[0];
  const float* K = (const float*)d_in[1];
  const float* V = (const float*)d_in[2];
  const unsigned char* M = (const unsigned char*)d_in[3];
  float* out = (float*)d_out;
  float* attn = out + (size_t)4 * 16 * S_LEN * DKD;

  const size_t BITS_SZ = (size_t)4 * S_LEN * 32 * 8;              // 2 MB
  const size_t KWS_SZ  = (size_t)64 * NKT * BK * DKD * 2;         // 16 MB
  const size_t VWS_SZ  = (size_t)64 * NKT * DKD * BK * 2;         // 16 MB
  if (ws_size >= BITS_SZ + KWS_SZ + VWS_SZ) {
    u64t* bits = (u64t*)d_ws;
    u16t* Kws = (u16t*)((char*)d_ws + BITS_SZ);
    u16t* Vws = (u16t*)((char*)d_ws + BITS_SZ + KWS_SZ);
    prologue<<<3072, 256, 0, stream>>>(M, K, V, bits, Kws, Vws);
    attn_ws<<<2048, BDIM, 0, stream>>>(Q, Kws, Vws, bits, out, attn);
  } else {
    attn_fb<<<2048, BDIM, 0, stream>>>(Q, K, V, M, out, attn);
  }
}

// Round 9
// 337.020 us; speedup vs baseline: 2.9732x; 1.0036x over previous
//
#include <hip/hip_runtime.h>
#include <cstdint>
#include <cstddef>

// Problem: B=4, H=16, S=2048, DK=64; out = (attn@V, attn), fp32.
#define S_LEN 2048
#define DKD   64
#define BQ    64
#define BK    128
#define NKT   16
#define BDIM  256

typedef float f32x4 __attribute__((ext_vector_type(4)));
typedef short s16x8 __attribute__((ext_vector_type(8)));
typedef short s16x4 __attribute__((ext_vector_type(4)));
typedef unsigned int u32x4 __attribute__((ext_vector_type(4)));
typedef unsigned short u16t;
typedef unsigned long long u64t;

// ---- LDS layout for attn_ws (bytes) ----
#define KS_OFF    0
#define KT_BYTES  (BK * DKD * 2)              // 16384, linear rows of 128B
#define VT_OFF    16384                        // phase2: V^T tile; phase1: K buffer 1
#define VT_BYTES  (DKD * BK * 2)              // 16384, linear rows of 256B
#define PS_OFF    32768
#define PS_STRIDE 280
#define SMEM_SZ   (PS_OFF + BQ * PS_STRIDE)   // 50688 -> 3 blocks/CU

__device__ __forceinline__ u16t f2bf(float f) {  // RNE fp32->bf16
  unsigned u = __builtin_bit_cast(unsigned, f);
  return (u16t)((u + 0x7FFFu + ((u >> 16) & 1u)) >> 16);
}
__device__ __forceinline__ float bf_lo(unsigned u) {
  return __builtin_bit_cast(float, u << 16);
}
__device__ __forceinline__ float bf_hi(unsigned u) {
  return __builtin_bit_cast(float, u & 0xFFFF0000u);
}

__device__ __forceinline__ void gl_lds16(const void* g, void* l) {
  typedef __attribute__((address_space(1))) void gvoid;
  typedef __attribute__((address_space(3))) void lvoid;
  __builtin_amdgcn_global_load_lds((gvoid*)(void*)g, (lvoid*)l, 16, 0, 0);
}

// counted barriers. sched_barrier(0) after, per rule #18.
#define BAR_VM(N) do { asm volatile("s_waitcnt vmcnt(" #N ")\n\ts_barrier" ::: "memory"); \
                       __builtin_amdgcn_sched_barrier(0); } while (0)
#define BAR_LG()  do { asm volatile("s_waitcnt lgkmcnt(0)\n\ts_barrier" ::: "memory"); \
                       __builtin_amdgcn_sched_barrier(0); } while (0)
#define BAR_VM8() do { asm volatile("s_waitcnt vmcnt(8) lgkmcnt(0)\n\ts_barrier" ::: "memory"); \
                       __builtin_amdgcn_sched_barrier(0); } while (0)

// ---------- fused prologue: pack mask bits + K->bf16 tiles + V->bf16^T tiles ----------
__global__ __launch_bounds__(256)
void prologue(const unsigned char* __restrict__ Mg, const float* __restrict__ Kg,
              const float* __restrict__ Vg, u64t* __restrict__ bits,
              u16t* __restrict__ Kws, u16t* __restrict__ Vws) {
  __shared__ float scr[BK][DKD + 1];
  __shared__ int mflag_s;
  const int tid = threadIdx.x;
  const int bid = blockIdx.x;

  if (bid < 1024) {            // ---- pack mask -> 1 bit per element ----
    int f = 0;                 // bool(1B) vs int32(4B) detection
    for (int i = tid; i < 4096; i += 256) if ((i & 3) && Mg[i]) f = 1;
    if (tid == 0) mflag_s = 0;
    __syncthreads();
    if (f) mflag_s = 1;
    __syncthreads();
    const int mstride = mflag_s ? 1 : 4;

    const int row = bid * 8 + (tid >> 5);    // 8192 rows (b*S+q)
    const int wd  = tid & 31;
    const size_t kbase = (size_t)row * S_LEN + (size_t)wd * 64;
    u64t word = 0;
    if (mstride == 1) {
      const u64t* p = (const u64t*)(Mg + kbase);
      #pragma unroll
      for (int i = 0; i < 8; ++i) {
        u64t x = p[i];
        u64t nz = x | (x >> 4); nz |= nz >> 2; nz |= nz >> 1;
        nz &= 0x0101010101010101ull;
        word |= ((nz * 0x0102040810204080ull) >> 56) << (8 * i);
      }
    } else {
      const unsigned* p = (const unsigned*)Mg + kbase;
      #pragma unroll
      for (int i = 0; i < 64; ++i) word |= (u64t)(p[i] ? 1u : 0u) << i;
    }
    bits[(size_t)row * 32 + wd] = word;
  } else if (bid < 2048) {     // ---- K fp32 -> bf16 tiles, 16B-chunk XOR-permuted ----
    const int kb = bid - 1024;
    const float* src = Kg + (size_t)kb * (BK * DKD);
    u16t* dst = Kws + (size_t)kb * (BK * DKD);
    #pragma unroll
    for (int i = 0; i < 4; ++i) {
      int c = tid + 256 * i;                 // 1024 chunks of 8 elems (16B)
      int row = c >> 3, y = c & 7;
      int oc = y ^ (row & 7);
      const float4* s4 = (const float4*)(src + row * DKD + 8 * oc);
      float4 a = s4[0], b = s4[1];
      s16x8 h = { (short)f2bf(a.x), (short)f2bf(a.y), (short)f2bf(a.z), (short)f2bf(a.w),
                  (short)f2bf(b.x), (short)f2bf(b.y), (short)f2bf(b.z), (short)f2bf(b.w) };
      *(s16x8*)(dst + row * DKD + 8 * y) = h;
    }
  } else {                     // ---- V fp32 [k][dv] -> bf16 V^T tiles, 8B-chunk XOR-permuted ----
    const int vb = bid - 2048;
    const float4* src = (const float4*)(Vg + (size_t)vb * (BK * DKD));
    #pragma unroll
    for (int i = 0; i < 8; ++i) {
      int c = tid + 256 * i;
      float4 v = src[c];
      int k = c >> 4, d0 = (c & 15) * 4;
      scr[k][d0] = v.x; scr[k][d0 + 1] = v.y; scr[k][d0 + 2] = v.z; scr[k][d0 + 3] = v.w;
    }
    __syncthreads();
    u16t* dst = Vws + (size_t)vb * (DKD * BK);
    #pragma unroll
    for (int i = 0; i < 8; ++i) {
      int c = tid + 256 * i;                 // 2048 chunks of 4 elems (8B)
      int dv = c >> 5, y = c & 31;
      int k0 = 4 * (y ^ (dv & 7));
      ushort4 h = make_ushort4(f2bf(scr[k0][dv]), f2bf(scr[k0 + 1][dv]),
                               f2bf(scr[k0 + 2][dv]), f2bf(scr[k0 + 3][dv]));
      *(ushort4*)(dst + dv * BK + 4 * y) = h;
    }
  }
}

// ---------- fused attention, ws path (swapped QK^T: P is lane-local) ----------
__global__ __launch_bounds__(256)
void attn_ws(const float* __restrict__ Qg, const u16t* __restrict__ Kws,
             const u16t* __restrict__ Vws, const u64t* __restrict__ bits,
             float* __restrict__ outg, float* __restrict__ attng) {
  __shared__ char smem[SMEM_SZ];
  const int tid = threadIdx.x;
  const int p = blockIdx.x;
  const int qb = (p >> 3) & 31;                 // XCD swizzle: bh pinned per XCD
  const int bh = (p & 7) + 8 * (p >> 8);
  const int b  = bh >> 4;
  const int lane = tid & 63, wv = tid >> 6;
  const int cl = lane & 15, g = lane >> 4;
  const int qrow = qb * BQ + 16 * wv + cl;      // this lane's q row (swapped layout)
  const int swzK = (cl & 7) << 4;               // read-side XOR, 16B chunks
  const int swzV = (cl & 7) << 3;               // read-side XOR, 8B chunks

  const char* Kbh = (const char*)Kws + (size_t)bh * NKT * KT_BYTES;
  const char* Vbh = (const char*)Vws + (size_t)bh * NKT * VT_BYTES;
  const u64t* bitR = bits + (size_t)(b * S_LEN + qrow) * 32;
  float* attnQ = attng + ((size_t)bh * S_LEN + (size_t)qb * BQ) * S_LEN;

  // Q B-fragments straight from fp32 Q (one-time). 1/8 scale folded into Q:
  // bf16(Q/8) == bf16(Q)/8 exactly (pure exponent shift), so QK^T acc is pre-scaled.
  s16x8 aq0, aq1;
  {
    const float* qr = Qg + ((size_t)bh * S_LEN + qrow) * DKD;
    float x[8], y[8];
    *(float4*)(x)     = *(const float4*)(qr + 8 * g);
    *(float4*)(x + 4) = *(const float4*)(qr + 8 * g + 4);
    *(float4*)(y)     = *(const float4*)(qr + 32 + 8 * g);
    *(float4*)(y + 4) = *(const float4*)(qr + 32 + 8 * g + 4);
    #pragma unroll
    for (int j = 0; j < 8; ++j) {
      aq0[j] = (short)f2bf(x[j] * 0.125f);
      aq1[j] = (short)f2bf(y[j] * 0.125f);
    }
  }

  auto stageK = [&](int kt, int off) {
    const char* src = Kbh + (size_t)kt * KT_BYTES + wv * 4096 + lane * 16;
    #pragma unroll
    for (int t = 0; t < 4; ++t)
      gl_lds16(src + t * 1024, (void*)(smem + off + wv * 4096 + t * 1024));
  };
  auto stageV = [&](int kt) {
    const char* src = Vbh + (size_t)kt * VT_BYTES + wv * 4096 + lane * 16;
    #pragma unroll
    for (int t = 0; t < 4; ++t)
      gl_lds16(src + t * 1024, (void*)(smem + VT_OFF + wv * 4096 + t * 1024));
  };

  // ================= phase 1: row-sums (no-max softmax), K dbuf =================
  // T3-min single-barrier loop: stage(next) -> compute(cur) -> vmcnt(0)+barrier.
  // Safe: by barrier arrival every wave's ds_reads of cur were consumed by MFMA,
  // so next iteration's stage into the other buffer cannot race reads.
  float lsum = 0.f;
  stageK(0, KS_OFF);
  BAR_VM(0);                       // tile 0 resident for all waves
  for (int kt = 0; kt < NKT; ++kt) {
    const int cur = (kt & 1) ? VT_OFF : KS_OFF;
    if (kt + 1 < NKT) stageK(kt + 1, (kt & 1) ? KS_OFF : VT_OFF);
    ulonglong2 bw = *(const ulonglong2*)(bitR + 2 * kt);
    #pragma unroll
    for (int s = 0; s < 8; ++s) {
      const char* rb = smem + cur + (16 * s + cl) * 128;
      s16x8 k0 = *(const s16x8*)(rb + ((16 * g) ^ swzK));
      s16x8 k1 = *(const s16x8*)(rb + ((64 + 16 * g) ^ swzK));
      f32x4 acc = {0.f, 0.f, 0.f, 0.f};
      acc = __builtin_amdgcn_mfma_f32_16x16x32_bf16(k0, aq0, acc, 0, 0, 0);  // S^T (pre-scaled)
      acc = __builtin_amdgcn_mfma_f32_16x16x32_bf16(k1, aq1, acc, 0, 0, 0);
      unsigned nib = (unsigned)(((s < 4) ? bw.x : bw.y) >> (16 * (s & 3) + 4 * g)) & 0xFu;
      #pragma unroll
      for (int r = 0; r < 4; ++r)
        lsum += ((nib >> r) & 1) ? 0.f : __expf(acc[r]);
    }
    if (kt + 1 < NKT) BAR_VM(0);   // next tile arrived; single barrier per kt
  }
  BAR_LG();                        // all waves done reading last tile
  stageK(0, KS_OFF);               // stage K0/V0 for phase 2; reduce meanwhile
  stageV(0);
  lsum += __shfl_xor(lsum, 16);
  lsum += __shfl_xor(lsum, 32);
  const float rinv = 1.f / lsum;
  BAR_VM(0);

  // ================= phase 2: recompute, in-reg pa, PV, attn write =================
  f32x4 accpv[4];
  #pragma unroll
  for (int db = 0; db < 4; ++db) accpv[db] = (f32x4){0.f, 0.f, 0.f, 0.f};

  for (int kt = 0; kt < NKT; ++kt) {
    // entering: K/V for kt resident; PS free
    ulonglong2 bw = *(const ulonglong2*)(bitR + 2 * kt);
    char* pbase = smem + PS_OFF + (16 * wv + cl) * PS_STRIDE;

    #pragma unroll
    for (int ks = 0; ks < 4; ++ks) {
      f32x4 qa[2];
      __builtin_amdgcn_s_setprio(1);
      #pragma unroll
      for (int sp = 0; sp < 2; ++sp) {
        int s = 2 * ks + sp;
        const char* rb = smem + KS_OFF + (16 * s + cl) * 128;
        s16x8 k0 = *(const s16x8*)(rb + ((16 * g) ^ swzK));
        s16x8 k1 = *(const s16x8*)(rb + ((64 + 16 * g) ^ swzK));
        f32x4 acc = {0.f, 0.f, 0.f, 0.f};
        acc = __builtin_amdgcn_mfma_f32_16x16x32_bf16(k0, aq0, acc, 0, 0, 0);
        acc = __builtin_amdgcn_mfma_f32_16x16x32_bf16(k1, aq1, acc, 0, 0, 0);
        qa[sp] = acc;
      }
      __builtin_amdgcn_s_setprio(0);
      unsigned hw[4];
      #pragma unroll
      for (int sp = 0; sp < 2; ++sp) {
        int s = 2 * ks + sp;
        unsigned nib = (unsigned)(((s < 4) ? bw.x : bw.y) >> (16 * (s & 3) + 4 * g)) & 0xFu;
        #pragma unroll
        for (int rr = 0; rr < 2; ++rr) {
          float p0 = ((nib >> (2 * rr)) & 1)     ? 0.f : __expf(qa[sp][2 * rr]) * rinv;
          float p1 = ((nib >> (2 * rr + 1)) & 1) ? 0.f : __expf(qa[sp][2 * rr + 1]) * rinv;
          hw[2 * sp + rr] = (unsigned)f2bf(p0) | ((unsigned)f2bf(p1) << 16);
        }
      }
      // PS write (for attn readback only) + in-register pa for PV
      *(uint2*)(pbase + 64 * ks + 8 * g)      = make_uint2(hw[0], hw[1]);
      *(uint2*)(pbase + 64 * ks + 32 + 8 * g) = make_uint2(hw[2], hw[3]);
      s16x8 pa = __builtin_bit_cast(s16x8, (u32x4){hw[0], hw[1], hw[2], hw[3]});
      __builtin_amdgcn_s_setprio(1);
      #pragma unroll
      for (int db = 0; db < 4; ++db) {
        const char* vrow = smem + VT_OFF + (16 * db + cl) * 256;
        s16x4 v0 = *(const s16x4*)(vrow + ((64 * ks + 8 * g) ^ swzV));
        s16x4 v1 = *(const s16x4*)(vrow + ((64 * ks + 32 + 8 * g) ^ swzV));
        s16x8 vb = __builtin_shufflevector(v0, v1, 0, 1, 2, 3, 4, 5, 6, 7);
        accpv[db] = __builtin_amdgcn_mfma_f32_16x16x32_bf16(pa, vb, accpv[db], 0, 0, 0);
      }
      __builtin_amdgcn_s_setprio(0);
    }

    BAR_LG();                    // PS visible; K/V LDS reads complete

    if (kt + 1 < NKT) { stageK(kt + 1, KS_OFF); stageV(kt + 1); }   // 8 gl_lds

    // readback PS -> coalesced fp32 attn stores (kept in flight across barrier)
    #pragma unroll
    for (int i = 0; i < 4; ++i) {
      int c = tid + 256 * i;
      int q = c >> 4, ch = c & 15;
      u32x4 d = *(const u32x4*)(smem + PS_OFF + q * PS_STRIDE + ch * 16);
      f32x4 lo = { bf_lo(d.x), bf_hi(d.x), bf_lo(d.y), bf_hi(d.y) };
      f32x4 hi = { bf_lo(d.z), bf_hi(d.z), bf_lo(d.w), bf_hi(d.w) };
      float* dst = attnQ + (size_t)q * S_LEN + kt * BK + ch * 8;
      __builtin_nontemporal_store(lo, (f32x4*)dst);
      __builtin_nontemporal_store(hi, (f32x4*)(dst + 4));
    }

    if (kt + 1 < NKT) BAR_VM8(); // gl_lds retired (FIFO: 8 younger stores float)
  }

  // out: C rows (4g+r) = q, col (16db+cl) = dv
  const int q0 = qb * BQ + 16 * wv + 4 * g;
  #pragma unroll
  for (int r = 0; r < 4; ++r) {
    float* orow = outg + (size_t)(bh * S_LEN + q0 + r) * DKD + cl;
    #pragma unroll
    for (int db = 0; db < 4; ++db) orow[16 * db] = accpv[db][r];
  }
}

// ---------- fallback (self-contained, R2-proven structure) ----------
#define FB_KSTR 144
#define FB_VOFF (BK * FB_KSTR)
#define FB_VSTR 272
#define FB_POFF (FB_VOFF + DKD * FB_VSTR)
#define FB_SMEM (FB_POFF + BQ * FB_VSTR)

__global__ __launch_bounds__(256)
void attn_fb(const float* __restrict__ Qg, const float* __restrict__ Kg,
             const float* __restrict__ Vg, const unsigned char* __restrict__ Mg,
             float* __restrict__ outg, float* __restrict__ attng) {
  __shared__ char smem[FB_SMEM];
  __shared__ int mflag_s;
  const int tid = threadIdx.x;
  const int p = blockIdx.x;
  const int qb = (p >> 3) & 31;
  const int bh = (p & 7) + 8 * (p >> 8);
  const int b  = bh >> 4;

  int f = 0;
  for (int i = tid; i < 4096; i += BDIM) if ((i & 3) && Mg[i]) f = 1;
  if (tid == 0) mflag_s = 0;
  __syncthreads();
  if (f) mflag_s = 1;
  __syncthreads();
  const int mstride = mflag_s ? 1 : 4;

  const int lane = tid & 63, wv = tid >> 6;
  const int cl = lane & 15, g = lane >> 4;
  const int q0 = qb * BQ + 16 * wv + 4 * g;

  const float* Kbh = Kg + (size_t)bh * S_LEN * DKD;
  const float* Vbh = Vg + (size_t)bh * S_LEN * DKD;

  float* aRow[4]; float* oRow[4]; const unsigned char* mRow[4];
  #pragma unroll
  for (int r = 0; r < 4; ++r) {
    aRow[r] = attng + (size_t)(bh * S_LEN + q0 + r) * S_LEN + cl;
    oRow[r] = outg + (size_t)(bh * S_LEN + q0 + r) * DKD + cl;
    mRow[r] = Mg + ((size_t)(b * S_LEN + q0 + r) * S_LEN + cl) * (size_t)mstride;
  }

  s16x8 aq0, aq1;
  {
    const float* qrow = Qg + ((size_t)bh * S_LEN + qb * BQ + 16 * wv + cl) * DKD;
    float x[8], y[8];
    *(float4*)(x)     = *(const float4*)(qrow + 8 * g);
    *(float4*)(x + 4) = *(const float4*)(qrow + 8 * g + 4);
    *(float4*)(y)     = *(const float4*)(qrow + 32 + 8 * g);
    *(float4*)(y + 4) = *(const float4*)(qrow + 32 + 8 * g + 4);
    #pragma unroll
    for (int j = 0; j < 8; ++j) { aq0[j] = (short)f2bf(x[j]); aq1[j] = (short)f2bf(y[j]); }
  }

  float lsum[4] = {0.f, 0.f, 0.f, 0.f};
  for (int kt = 0; kt < NKT; ++kt) {
    const float4* ksrc = (const float4*)(Kbh + (size_t)kt * (BK * DKD));
    #pragma unroll
    for (int it = 0; it < 8; ++it) {
      int c = tid + BDIM * it;
      float4 v = ksrc[c];
      *(ushort4*)(smem + (c >> 4) * FB_KSTR + (c & 15) * 8) =
          make_ushort4(f2bf(v.x), f2bf(v.y), f2bf(v.z), f2bf(v.w));
    }
    __syncthreads();
    #pragma unroll
    for (int s = 0; s < 8; ++s) {
      s16x8 b0 = *(const s16x8*)(smem + (16 * s + cl) * FB_KSTR + 16 * g);
      s16x8 b1 = *(const s16x8*)(smem + (16 * s + cl) * FB_KSTR + 64 + 16 * g);
      f32x4 acc = {0.f, 0.f, 0.f, 0.f};
      acc = __builtin_amdgcn_mfma_f32_16x16x32_bf16(aq0, b0, acc, 0, 0, 0);
      acc = __builtin_amdgcn_mfma_f32_16x16x32_bf16(aq1, b1, acc, 0, 0, 0);
      #pragma unroll
      for (int r = 0; r < 4; ++r) {
        bool mk = mRow[r][(size_t)(kt * BK + 16 * s) * mstride] != 0;
        lsum[r] += mk ? 0.f : __expf(acc[r] * 0.125f);
      }
    }
    __syncthreads();
  }
  float rinv[4];
  #pragma unroll
  for (int r = 0; r < 4; ++r) {
    float l = lsum[r];
    #pragma unroll
    for (int d = 1; d < 16; d <<= 1) l += __shfl_xor(l, d);
    rinv[r] = 1.f / l;
  }

  f32x4 accpv[4];
  #pragma unroll
  for (int db = 0; db < 4; ++db) accpv[db] = (f32x4){0.f, 0.f, 0.f, 0.f};

  for (int kt = 0; kt < NKT; ++kt) {
    const float4* ksrc = (const float4*)(Kbh + (size_t)kt * (BK * DKD));
    #pragma unroll
    for (int it = 0; it < 8; ++it) {
      int c = tid + BDIM * it;
      float4 v = ksrc[c];
      *(ushort4*)(smem + (c >> 4) * FB_KSTR + (c & 15) * 8) =
          make_ushort4(f2bf(v.x), f2bf(v.y), f2bf(v.z), f2bf(v.w));
    }
    const float4* vsrc = (const float4*)(Vbh + (size_t)kt * (BK * DKD));
    #pragma unroll
    for (int it = 0; it < 8; ++it) {
      int c = tid + BDIM * it;
      float4 v = vsrc[c];
      int k = c >> 4, d0 = (c & 15) * 4;
      *(u16t*)(smem + FB_VOFF + (d0 + 0) * FB_VSTR + k * 2) = f2bf(v.x);
      *(u16t*)(smem + FB_VOFF + (d0 + 1) * FB_VSTR + k * 2) = f2bf(v.y);
      *(u16t*)(smem + FB_VOFF + (d0 + 2) * FB_VSTR + k * 2) = f2bf(v.z);
      *(u16t*)(smem + FB_VOFF + (d0 + 3) * FB_VSTR + k * 2) = f2bf(v.w);
    }
    __syncthreads();

    #pragma unroll
    for (int ks = 0; ks < 4; ++ks) {
      f32x4 qa[2];
      #pragma unroll
      for (int sp = 0; sp < 2; ++sp) {
        int s = 2 * ks + sp;
        s16x8 b0 = *(const s16x8*)(smem + (16 * s + cl) * FB_KSTR + 16 * g);
        s16x8 b1 = *(const s16x8*)(smem + (16 * s + cl) * FB_KSTR + 64 + 16 * g);
        f32x4 acc = {0.f, 0.f, 0.f, 0.f};
        acc = __builtin_amdgcn_mfma_f32_16x16x32_bf16(aq0, b0, acc, 0, 0, 0);
        acc = __builtin_amdgcn_mfma_f32_16x16x32_bf16(aq1, b1, acc, 0, 0, 0);
        qa[sp] = acc;
      }
      #pragma unroll
      for (int sp = 0; sp < 2; ++sp) {
        int s = 2 * ks + sp;
        #pragma unroll
        for (int r = 0; r < 4; ++r) {
          bool mk = mRow[r][(size_t)(kt * BK + 16 * s) * mstride] != 0;
          float pv = mk ? 0.f : __expf(qa[sp][r] * 0.125f) * rinv[r];
          __builtin_nontemporal_store(pv, aRow[r] + kt * BK + 16 * s);
          *(u16t*)(smem + FB_POFF + (16 * wv + 4 * g + r) * FB_VSTR +
                   (32 * ks + 16 * sp + cl) * 2) = f2bf(pv);
        }
      }
      s16x4 p0 = *(const s16x4*)(smem + FB_POFF + (16 * wv + cl) * FB_VSTR + (32 * ks + 4 * g) * 2);
      s16x4 p1 = *(const s16x4*)(smem + FB_POFF + (16 * wv + cl) * FB_VSTR + (32 * ks + 16 + 4 * g) * 2);
      s16x8 pa = __builtin_shufflevector(p0, p1, 0, 1, 2, 3, 4, 5, 6, 7);
      #pragma unroll
      for (int db = 0; db < 4; ++db) {
        s16x4 v0 = *(const s16x4*)(smem + FB_VOFF + (16 * db + cl) * FB_VSTR + (32 * ks + 4 * g) * 2);
        s16x4 v1 = *(const s16x4*)(smem + FB_VOFF + (16 * db + cl) * FB_VSTR + (32 * ks + 16 + 4 * g) * 2);
        s16x8 vb = __builtin_shufflevector(v0, v1, 0, 1, 2, 3, 4, 5, 6, 7);
        accpv[db] = __builtin_amdgcn_mfma_f32_16x16x32_bf16(pa, vb, accpv[db], 0, 0, 0);
      }
    }
    __syncthreads();
  }

  #pragma unroll
  for (int db = 0; db < 4; ++db)
    #pragma unroll
    for (int r = 0; r < 4; ++r)
      oRow[r][16 * db] = accpv[db][r];
}

extern "C" void kernel_launch(void* const* d_in, const int* in_sizes, int n_in,
                              void* d_out, int out_size, void* d_ws, size_t ws_size,
                              hipStream_t stream) {
  const float* Q = (const float*)d_in[0];
  const float* K = (const float*)d_in[1];
  const float* V = (const float*)d_in[2];
  const unsigned char* M = (const unsigned char*)d_in[3];
  float* out = (float*)d_out;
  float* attn = out + (size_t)4 * 16 * S_LEN * DKD;

  const size_t BITS_SZ = (size_t)4 * S_LEN * 32 * 8;              // 2 MB
  const size_t KWS_SZ  = (size_t)64 * NKT * BK * DKD * 2;         // 16 MB
  const size_t VWS_SZ  = (size_t)64 * NKT * DKD * BK * 2;         // 16 MB
  if (ws_size >= BITS_SZ + KWS_SZ + VWS_SZ) {
    u64t* bits = (u64t*)d_ws;
    u16t* Kws = (u16t*)((char*)d_ws + BITS_SZ);
    u16t* Vws = (u16t*)((char*)d_ws + BITS_SZ + KWS_SZ);
    prologue<<<3072, 256, 0, stream>>>(M, K, V, bits, Kws, Vws);
    attn_ws<<<2048, BDIM, 0, stream>>>(Q, Kws, Vws, bits, out, attn);
  } else {
    attn_fb<<<2048, BDIM, 0, stream>>>(Q, K, V, M, out, attn);
  }
}